// Round 5
// baseline (209.969 us; speedup 1.0000x reference)
//
#include <hip/hip_runtime.h>

// TriangleLinear: out[b][8191-r] = bias[r] + sum_{c>=max(0,r-4)} W_packed[...] * x[b][c]
// HBM floor: 134.4 MB packed-weight stream read once => ~21 us kernel.
//
// Measurement model: dur_us ~= kernel + ~156 us of harness re-poison fills (the
// rocprof top-5 shows only 77-80us fillBufferAligned dispatches; our kernel < 77us).
//   R0 packed+nt scalar w:            ~41 us kernel (197 total)
//   R2 strided no-nt scalar:          ~52 us (208)   -> dropping nt cost ~10us
//   R3 packed no-nt scalar+prefetch:  ~51 us (207)   -> prefetch alone ~1us
// R0's 41us matches a VMEM-issue model: 24 wave64 VMEM instr/tile (16 scalar w
// stride-16B touching 16 lines each + 8 float4 x) x 16cyc x 8 tiles x 32 waves/CU
// ~= 98K cyc ~= 41us. The kernel is VMEM-instruction bound, not BW bound.
//
// R4/R5: vectorize w loads to 16B (global_load_dwordx4). Packed rows are only 4B
// aligned, but CDNA runs in unaligned-access mode: dword-aligned dwordx4 is
// architecturally supported; lanes stay contiguous (fully-used 1KB bursts).
// 24 -> 12 VMEM instr/tile, w line-touches /4. Keep nt (read-once stream) and
// the register double-buffer. Predicted kernel ~22-26us => dur_us ~180.
// (R5 = R4 resubmitted: round-4 "container failed twice" matches round-1's
// pure-infra failure signature; no measurement was produced.)

constexpr int N = 8192;      // N_IN == N_OUT
constexpr int BATCH = 8;
constexpr int ROWS = 4;      // rows per block: x loads shared across rows in registers
constexpr int THREADS = 256;
constexpr int VEC = 4;       // columns per thread (packed: float4 x loads)
constexpr int TILE = THREADS * VEC;  // 1024 columns per block-iteration

typedef float f32x4 __attribute__((ext_vector_type(4)));

__global__ __launch_bounds__(THREADS, 4)
void tri_linear_kernel(const float* __restrict__ x,
                       const float* __restrict__ w,
                       const float* __restrict__ bias,
                       float* __restrict__ out) {
  const int t = threadIdx.x;
  const int r0 = blockIdx.x * ROWS;

  // Per-row triangular start column and packed-row base pointers (uniform -> SGPR).
  int c0[ROWS];
  const float* wrow[ROWS];
#pragma unroll
  for (int i = 0; i < ROWS; ++i) {
    const int r = r0 + i;
    c0[i] = (r > 4) ? (r - 4) : 0;
    // off(r) = 8192*r - (r-5)(r-4)/2 for r>=5, else 8192*r. (off(8192)=33,591,286 = nW)
    long long off = (r <= 5)
        ? (long long)r * N
        : (long long)r * N - ((long long)(r - 5) * (long long)(r - 4)) / 2;
    wrow[i] = w + (off - (long long)c0[i]);   // wrow[i][c] valid for c in [c0[i], N)
  }
  const int cbA = c0[0] & ~(TILE - 1);        // c0[0] == min c0 of this block's rows
  // c0[0] = r0-4 is a multiple of 4, so c0[i] <= c0[0]+3 <= cbA+1023: every row's
  // triangular start falls inside the edge tile; main loop needs no predicate.

  float acc[ROWS][BATCH];
#pragma unroll
  for (int i = 0; i < ROWS; ++i)
#pragma unroll
    for (int b = 0; b < BATCH; ++b) acc[i][b] = 0.0f;

  const int c4 = VEC * t;   // this thread's packed column offset within a tile

  // ---- Edge tile [cbA, cbA+TILE): predicated on the triangular boundary ----
  {
    const int c = cbA + c4;
    float4 xv[BATCH];
#pragma unroll
    for (int b = 0; b < BATCH; ++b)
      xv[b] = *(const float4*)(x + b * N + c);
#pragma unroll
    for (int i = 0; i < ROWS; ++i) {
#pragma unroll
      for (int j = 0; j < VEC; ++j) {
        const int cj = c + j;
        const float wv = (cj >= c0[i]) ? __builtin_nontemporal_load(wrow[i] + cj)
                                       : 0.0f;
        const float* xe;
#pragma unroll
        for (int b = 0; b < BATCH; ++b) {
          xe = reinterpret_cast<const float*>(&xv[b]);
          acc[i][b] = fmaf(wv, xe[j], acc[i][b]);
        }
      }
    }
  }

  // ---- Main loop: predicate-free; w as 16B nt vector loads, double-buffered ----
  int cb = cbA + TILE;
  if (cb < N) {
    f32x4 wbuf[ROWS];
#pragma unroll
    for (int i = 0; i < ROWS; ++i)
      wbuf[i] = __builtin_nontemporal_load(
          reinterpret_cast<const f32x4*>(wrow[i] + cb + c4));  // 4B-aligned x4: OK in
                                                               // HW unaligned mode
#pragma unroll 2
    for (; cb + TILE < N; cb += TILE) {
      const int c = cb + c4;
      float4 xv[BATCH];
#pragma unroll
      for (int b = 0; b < BATCH; ++b)
        xv[b] = *(const float4*)(x + b * N + c);   // L2-hot
      f32x4 wnxt[ROWS];
#pragma unroll
      for (int i = 0; i < ROWS; ++i)
        wnxt[i] = __builtin_nontemporal_load(
            reinterpret_cast<const f32x4*>(wrow[i] + c + TILE));  // HBM, in flight
#pragma unroll
      for (int i = 0; i < ROWS; ++i)
#pragma unroll
        for (int j = 0; j < VEC; ++j) {
          const float* xe;
#pragma unroll
          for (int b = 0; b < BATCH; ++b) {
            xe = reinterpret_cast<const float*>(&xv[b]);
            acc[i][b] = fmaf(wbuf[i][j], xe[j], acc[i][b]);
          }
        }
#pragma unroll
      for (int i = 0; i < ROWS; ++i)
        wbuf[i] = wnxt[i];                          // rotate (elided by unroll 2)
    }

    // ---- Tail tile: FMA the preloaded buffer, no further prefetch ----
    {
      const int c = cb + c4;
      float4 xv[BATCH];
#pragma unroll
      for (int b = 0; b < BATCH; ++b)
        xv[b] = *(const float4*)(x + b * N + c);
#pragma unroll
      for (int i = 0; i < ROWS; ++i)
#pragma unroll
        for (int j = 0; j < VEC; ++j) {
          const float* xe;
#pragma unroll
          for (int b = 0; b < BATCH; ++b) {
            xe = reinterpret_cast<const float*>(&xv[b]);
            acc[i][b] = fmaf(wbuf[i][j], xe[j], acc[i][b]);
          }
        }
    }
  }

  // ---- Reduction: 32 (row,batch) sums over 256 threads, transposed LDS tile ----
  // red[256][33] = 33.8 KB (4 blocks/CU). Pad 33 -> write bank (t + s) % 32 (2-way,
  // free) and read bank (k + s) % 32 with s spanning 0..31 across the wave (2-way, free).
  __shared__ float red[THREADS][ROWS * BATCH + 1];
#pragma unroll
  for (int i = 0; i < ROWS; ++i)
#pragma unroll
    for (int b = 0; b < BATCH; ++b)
      red[t][i * BATCH + b] = acc[i][b];
  __syncthreads();

  const int s = t & 31;     // which (row,batch) sum
  const int part = t >> 5;  // which 32-thread chunk
  float p = 0.0f;
#pragma unroll
  for (int k = 0; k < 32; ++k) p += red[part * 32 + k][s];

  __shared__ float red2[32][9];
  red2[s][part] = p;
  __syncthreads();

  if (t < 32) {
    float total = 0.0f;
#pragma unroll
    for (int g = 0; g < 8; ++g) total += red2[t][g];
    const int i = t >> 3, b = t & 7;   // t == i*BATCH + b == s
    const int r = r0 + i;
    out[b * N + (N - 1 - r)] = total + bias[r];  // last-dim flip + bias
  }
}

extern "C" void kernel_launch(void* const* d_in, const int* in_sizes, int n_in,
                              void* d_out, int out_size, void* d_ws, size_t ws_size,
                              hipStream_t stream) {
  const float* x    = (const float*)d_in[0];  // [8, 8192]
  const float* w    = (const float*)d_in[1];  // [33591286] packed triangular
  const float* bias = (const float*)d_in[2];  // [8192]
  float* out = (float*)d_out;                 // [8, 8192]
  tri_linear_kernel<<<N / ROWS, THREADS, 0, stream>>>(x, w, bias, out);
}

// Round 6
// 196.808 us; speedup vs baseline: 1.0669x; 1.0669x over previous
//
#include <hip/hip_runtime.h>

// TriangleLinear: out[b][8191-r] = bias[r] + sum_{c>=max(0,r-4)} W_packed[...] * x[b][c]
// HBM floor: 134.4 MB packed-weight stream read once => ~21 us kernel.
//
// Measurement model: dur_us ~= kernel + ~156 us harness re-poison fills (rocprof
// top-5 shows only 77-80us fillBufferAligned; our kernel dispatch < 77us).
//   R0 scalar w + nt, simple loop:   ~41 us  (197)   <- best
//   R2 scalar strided, no-nt:        ~52 us  (208)   (2x VMEM instr count)
//   R3 scalar + manual dbuf, no-nt:  ~51 us  (207)   (dbuf +16 VGPR -> spill/sched)
//   R5 dwordx4 + nt + manual dbuf:   ~54 us  (210)   (same dbuf poison; but PROVES
//                                                     4B-aligned dwordx4 is correct)
// Line-touch model (VMEM path ~1 line/cyc/CU): R0 = 24 instr x 16 line-touches
// = 384 cyc/tile/wave -> 98K cyc/CU -> 41 us. Matches. The scalar w j-family
// touches every 64B line 4x and nt blocks L1 absorption.
//
// R6 = R0 + ONE change: 16 scalar nt w loads -> 4 nt dwordx4 (f32x4) loads.
// No manual dbuf (R3/R5's poison), compiler pipelines the simple loop itself.
// w line-touches /4: ~196 cyc/tile/wave -> ~21-27 us kernel -> dur_us ~180.

constexpr int N = 8192;      // N_IN == N_OUT
constexpr int BATCH = 8;
constexpr int ROWS = 4;      // rows per block: x loads shared across rows in registers
constexpr int THREADS = 256;
constexpr int VEC = 4;       // columns per thread (packed: float4 x loads)
constexpr int TILE = THREADS * VEC;  // 1024 columns per block-iteration

typedef float f32x4 __attribute__((ext_vector_type(4)));

__global__ __launch_bounds__(THREADS, 4)
void tri_linear_kernel(const float* __restrict__ x,
                       const float* __restrict__ w,
                       const float* __restrict__ bias,
                       float* __restrict__ out) {
  const int t = threadIdx.x;
  const int r0 = blockIdx.x * ROWS;

  // Per-row triangular start column and packed-row base pointers (uniform -> SGPR).
  int c0[ROWS];
  const float* wrow[ROWS];
#pragma unroll
  for (int i = 0; i < ROWS; ++i) {
    const int r = r0 + i;
    c0[i] = (r > 4) ? (r - 4) : 0;
    // off(r) = 8192*r - (r-5)(r-4)/2 for r>=5, else 8192*r. (off(8192)=33,591,286 = nW)
    long long off = (r <= 5)
        ? (long long)r * N
        : (long long)r * N - ((long long)(r - 5) * (long long)(r - 4)) / 2;
    wrow[i] = w + (off - (long long)c0[i]);   // wrow[i][c] valid for c in [c0[i], N)
  }
  const int cbA = c0[0] & ~(TILE - 1);        // c0[0] == min c0 of this block's rows
  // c0[0] = r0-4 is a multiple of 4, so c0[i] <= c0[0]+3 <= cbA+1023: every row's
  // triangular start falls inside the edge tile; main loop needs no predicate.

  float acc[ROWS][BATCH];
#pragma unroll
  for (int i = 0; i < ROWS; ++i)
#pragma unroll
    for (int b = 0; b < BATCH; ++b) acc[i][b] = 0.0f;

  const int c4 = VEC * t;   // this thread's packed column offset within a tile

  // ---- Edge tile [cbA, cbA+TILE): predicated on the triangular boundary ----
  {
    const int c = cbA + c4;
    float4 xv[BATCH];
#pragma unroll
    for (int b = 0; b < BATCH; ++b)
      xv[b] = *(const float4*)(x + b * N + c);
#pragma unroll
    for (int i = 0; i < ROWS; ++i) {
#pragma unroll
      for (int j = 0; j < VEC; ++j) {
        const int cj = c + j;
        const float wv = (cj >= c0[i]) ? __builtin_nontemporal_load(wrow[i] + cj)
                                       : 0.0f;
        const float* xe;
#pragma unroll
        for (int b = 0; b < BATCH; ++b) {
          xe = reinterpret_cast<const float*>(&xv[b]);
          acc[i][b] = fmaf(wv, xe[j], acc[i][b]);
        }
      }
    }
  }

  // ---- Main loop: predicate-free; w as 16B nt vector loads; NO manual dbuf ----
  // (R3/R5 showed the manual double-buffer costs ~10us: +16 VGPR past the 128 cap
  //  and it defeats the compiler's own pipelining of this simple loop.)
  for (int cb = cbA + TILE; cb < N; cb += TILE) {
    const int c = cb + c4;
    float4 xv[BATCH];
#pragma unroll
    for (int b = 0; b < BATCH; ++b)
      xv[b] = *(const float4*)(x + b * N + c);   // L2-hot
    f32x4 wv4[ROWS];
#pragma unroll
    for (int i = 0; i < ROWS; ++i)
      wv4[i] = __builtin_nontemporal_load(
          reinterpret_cast<const f32x4*>(wrow[i] + c));  // 4B-aligned x4: HW
                                                         // unaligned mode (R5-verified)
#pragma unroll
    for (int i = 0; i < ROWS; ++i)
#pragma unroll
      for (int j = 0; j < VEC; ++j) {
        const float* xe;
#pragma unroll
        for (int b = 0; b < BATCH; ++b) {
          xe = reinterpret_cast<const float*>(&xv[b]);
          acc[i][b] = fmaf(wv4[i][j], xe[j], acc[i][b]);
        }
      }
  }

  // ---- Reduction: 32 (row,batch) sums over 256 threads, transposed LDS tile ----
  // red[256][33] = 33.8 KB (4 blocks/CU). Pad 33 -> write bank (t + s) % 32 (2-way,
  // free) and read bank (k + s) % 32 with s spanning 0..31 across the wave (2-way, free).
  __shared__ float red[THREADS][ROWS * BATCH + 1];
#pragma unroll
  for (int i = 0; i < ROWS; ++i)
#pragma unroll
    for (int b = 0; b < BATCH; ++b)
      red[t][i * BATCH + b] = acc[i][b];
  __syncthreads();

  const int s = t & 31;     // which (row,batch) sum
  const int part = t >> 5;  // which 32-thread chunk
  float p = 0.0f;
#pragma unroll
  for (int k = 0; k < 32; ++k) p += red[part * 32 + k][s];

  __shared__ float red2[32][9];
  red2[s][part] = p;
  __syncthreads();

  if (t < 32) {
    float total = 0.0f;
#pragma unroll
    for (int g = 0; g < 8; ++g) total += red2[t][g];
    const int i = t >> 3, b = t & 7;   // t == i*BATCH + b == s
    const int r = r0 + i;
    out[b * N + (N - 1 - r)] = total + bias[r];  // last-dim flip + bias
  }
}

extern "C" void kernel_launch(void* const* d_in, const int* in_sizes, int n_in,
                              void* d_out, int out_size, void* d_ws, size_t ws_size,
                              hipStream_t stream) {
  const float* x    = (const float*)d_in[0];  // [8, 8192]
  const float* w    = (const float*)d_in[1];  // [33591286] packed triangular
  const float* bias = (const float*)d_in[2];  // [8192]
  float* out = (float*)d_out;                 // [8, 8192]
  tri_linear_kernel<<<N / ROWS, THREADS, 0, stream>>>(x, w, bias, out);
}